// Round 7
// baseline (140.535 us; speedup 1.0000x reference)
//
#include <hip/hip_runtime.h>
#include <math.h>

// x: (512, 3, 32, 32) fp32
// layer1: C=3 -> F=32, R=16, 3x3  -> (512,32,30,30)
// layer2: C=32 -> F=32, R=16, 3x3 -> (512,32,28,28)
// classifier: 25088 -> 10, then log_softmax
//
// Algebraic fusion (h1, h2 never materialized):
//   M[r1][r2] = sum_f l1_f0[f][r1] * l2_f3[f][r2]                 (16x16)
//   Wc2Q[n][q][r2][lr][c] = sum_f l2_f0[f][r2]*W_cls[n][f*784+(7q+lr)*28+c]
// Wc2Q matches the per-quarter t2 LDS order -> stage 5 is linear float4.
//
// Round-7 structure: one block per image-QUARTER (7 t2 rows + halo),
// NT=256, __launch_bounds__(256,3) (VGPR cap 170 >> natural ~90 -> no
// strangulation; rounds 3/6 proved caps below natural pressure lose).
// LDS ~43.6 KB -> 3 blocks/CU = 12 waves/CU with DECORRELATED barriers
// (when one block drains, two others issue). Quarters meet via atomicAdd
// of logit partials; last-arriving quarter (Cnt==3) does log_softmax.

#define NT 256
#define S1S 34              // s1 row stride (floats)
#define S1R (11 * S1S)      // s1 rank stride = 374

__global__ void precomp_kernel(const float* __restrict__ l1_f0,
                               const float* __restrict__ l2_f0,
                               const float* __restrict__ l2_f3,
                               const float* __restrict__ Wcls,
                               float* __restrict__ Wc2Q,
                               float* __restrict__ Mm,
                               float* __restrict__ Lg,
                               unsigned int* __restrict__ Cnt) {
    int id = blockIdx.x * blockDim.x + threadIdx.x;
    if (id < 7840) {                      // 10 classes x 784 pixels
        int n = id / 784;
        int pix = id - n * 784;
        int row = pix / 28;
        int col = pix - row * 28;
        int q = row / 7;
        int lr = row - q * 7;
        const float* wrow = &Wcls[n * 25088 + pix];
        float acc[16];
#pragma unroll
        for (int r2 = 0; r2 < 16; ++r2) acc[r2] = 0.f;
#pragma unroll
        for (int f = 0; f < 32; ++f) {
            float wv = wrow[f * 784];
#pragma unroll
            for (int r2 = 0; r2 < 16; ++r2)
                acc[r2] += l2_f0[f * 16 + r2] * wv;
        }
        float* dst = &Wc2Q[n * 12544 + q * 3136 + lr * 28 + col];
#pragma unroll
        for (int r2 = 0; r2 < 16; ++r2)
            dst[r2 * 196] = acc[r2];
    }
    if (id < 256) {
        int r1 = id >> 4, r2 = id & 15;
        float acc = 0.f;
#pragma unroll
        for (int f = 0; f < 32; ++f)
            acc += l1_f0[f * 16 + r1] * l2_f3[f * 16 + r2];
        Mm[id] = acc;
    }
    if (id < 5120) Lg[id] = 0.f;
    if (id >= 5120 && id < 5632) Cnt[id - 5120] = 0u;
}

// Per-quarter geometry (q = blockIdx.x & 3):
//   s1: rows 7q .. 7q+10 (11 rows x 32 cols, stride 34)  16 x 374
//   t1/u: rows 7q .. 7q+8 (9 rows x 30 cols)             16 x 270
//   t2: rows 7q .. 7q+6  (7 rows x 28 cols)              16 x 196
__global__ __launch_bounds__(NT, 3) void fused_quarter_kernel(
    const float* __restrict__ x,
    const float* __restrict__ l1_f1, const float* __restrict__ l1_f2,
    const float* __restrict__ l1_f3,
    const float* __restrict__ l2_f1, const float* __restrict__ l2_f2,
    const float* __restrict__ Wc2Q, const float* __restrict__ Mm,
    const float* __restrict__ b_cls,
    float* __restrict__ Lg, unsigned int* __restrict__ Cnt,
    float* __restrict__ out) {
    __shared__ alignas(16) float sA[16 * S1R];   // s1, then u (16x270)   23.9 KB
    __shared__ alignas(16) float sB[16 * 270];   // t1, then t2 (16x196)  17.3 KB
    __shared__ float sw1[144];
    __shared__ float sw2[144];
    __shared__ alignas(16) float sM[256];        // M [r1][r2]
    __shared__ float sred[4 * 10];
    __shared__ float slog[10];
    __shared__ int sflag;

    const int tid = threadIdx.x;
    const int b = blockIdx.x >> 2;
    const int q = blockIdx.x & 3;

    // ---- stage 0: tables (overlaps stage 1's thread range; cheap) ----
    if (tid < 144) {
        int r = tid / 9, ij = tid - r * 9;
        int i = ij / 3, j = ij - i * 3;
        sw1[tid] = l1_f1[i * 16 + r] * l1_f2[j * 16 + r];
    }
    if (tid >= 112) {
        int t = tid - 112;                        // 0..143
        int r = t / 9, ij = t - r * 9;
        int i = ij / 3, j = ij - i * 3;
        sw2[t] = l2_f1[i * 16 + r] * l2_f2[j * 16 + r];
    }
    sM[tid] = Mm[tid];

    // ---- stage 1: s1[r][row][col] = sum_c x*f3; 176 thr x 2 px (352 px) ----
    if (tid < 176) {
        const int p = tid * 2;                    // 0..350
        const int row = p >> 5, col = p & 31;
        const int xbase = b * 3072 + q * 224 + p; // rows 7q.. contiguous
        float2 x0 = *(const float2*)&x[xbase];
        float2 x1 = *(const float2*)&x[xbase + 1024];
        float2 x2 = *(const float2*)&x[xbase + 2048];
        const int o = row * S1S + col;
#pragma unroll
        for (int r = 0; r < 16; ++r) {
            float f0 = l1_f3[r], f1 = l1_f3[16 + r], f2 = l1_f3[32 + r];
            *(float2*)&sA[r * S1R + o] =
                make_float2(x0.x * f0 + x1.x * f1 + x2.x * f2,
                            x0.y * f0 + x1.y * f1 + x2.y * f2);
        }
    }
    __syncthreads();

    // ---- stage 2: t1[r] = conv3x3(s1[r]); 240 thr: (r, colpair), 9 rows ----
    if (tid < 240) {
        const int r = tid / 15;
        const int pr = tid - r * 15;
        const int c = 2 * pr;                     // 0..28
        const float* wp = &sw1[r * 9];
        const float w0 = wp[0], w1 = wp[1], w2 = wp[2];
        const float w3 = wp[3], w4 = wp[4], w5 = wp[5];
        const float w6 = wp[6], w7 = wp[7], w8 = wp[8];
        const float* base = &sA[r * S1R + c];
        float2 aL = *(const float2*)&base[0];
        float2 aH = *(const float2*)&base[2];
        float2 bL = *(const float2*)&base[S1S];
        float2 bH = *(const float2*)&base[S1S + 2];
        float a0 = aL.x, a1 = aL.y, a2 = aH.x, a3 = aH.y;
        float b0 = bL.x, b1 = bL.y, b2 = bH.x, b3 = bH.y;
        float* op = &sB[r * 270 + c];
#pragma unroll
        for (int s = 0; s < 9; ++s) {
            const float* rp = base + (s + 2) * S1S;
            float2 cL = *(const float2*)&rp[0];
            float2 cH = *(const float2*)&rp[2];
            float o0 = w0 * a0 + w1 * a1 + w2 * a2
                     + w3 * b0 + w4 * b1 + w5 * b2
                     + w6 * cL.x + w7 * cL.y + w8 * cH.x;
            float o1 = w0 * a1 + w1 * a2 + w2 * a3
                     + w3 * b1 + w4 * b2 + w5 * b3
                     + w6 * cL.y + w7 * cH.x + w8 * cH.y;
            *(float2*)&op[s * 30] = make_float2(o0, o1);
            a0 = b0; a1 = b1; a2 = b2; a3 = b3;
            b0 = cL.x; b1 = cL.y; b2 = cH.x; b3 = cH.y;
        }
    }
    __syncthreads();

    // ---- stage 3: u[r2][p] = sum_r1 t1[r1][p]*M[r1][r2] -> sA
    // (tr = r2 quad, tp = px pair); 135 px-pairs, strided by 64 ----
    {
        const int tr = tid & 3;
        const int r2b = tr * 4;
        for (int tp = (tid >> 2); tp < 135; tp += 64) {
            const int p2 = tp * 2;
            float a00 = 0.f, a01 = 0.f;
            float a10 = 0.f, a11 = 0.f;
            float a20 = 0.f, a21 = 0.f;
            float a30 = 0.f, a31 = 0.f;
#pragma unroll
            for (int r1 = 0; r1 < 16; ++r1) {
                float2 tv = *(const float2*)&sB[r1 * 270 + p2];
                float4 mv = *(const float4*)&sM[r1 * 16 + r2b];
                a00 += mv.x * tv.x; a01 += mv.x * tv.y;
                a10 += mv.y * tv.x; a11 += mv.y * tv.y;
                a20 += mv.z * tv.x; a21 += mv.z * tv.y;
                a30 += mv.w * tv.x; a31 += mv.w * tv.y;
            }
            *(float2*)&sA[(r2b + 0) * 270 + p2] = make_float2(a00, a01);
            *(float2*)&sA[(r2b + 1) * 270 + p2] = make_float2(a10, a11);
            *(float2*)&sA[(r2b + 2) * 270 + p2] = make_float2(a20, a21);
            *(float2*)&sA[(r2b + 3) * 270 + p2] = make_float2(a30, a31);
        }
    }
    __syncthreads();

    // ---- stage 4: t2[r2] = conv3x3(u[r2]); 224 thr: (r2, colpair), 7 rows ----
    if (tid < 224) {
        const int r2 = tid / 14;
        const int pr = tid - r2 * 14;
        const int c = 2 * pr;                     // 0..26
        const float* wp = &sw2[r2 * 9];
        const float w0 = wp[0], w1 = wp[1], w2 = wp[2];
        const float w3 = wp[3], w4 = wp[4], w5 = wp[5];
        const float w6 = wp[6], w7 = wp[7], w8 = wp[8];
        const float* base = &sA[r2 * 270 + c];
        float2 aL = *(const float2*)&base[0];
        float2 aH = *(const float2*)&base[2];
        float2 bL = *(const float2*)&base[30];
        float2 bH = *(const float2*)&base[32];
        float a0 = aL.x, a1 = aL.y, a2 = aH.x, a3 = aH.y;
        float b0 = bL.x, b1 = bL.y, b2 = bH.x, b3 = bH.y;
        float* op = &sB[r2 * 196 + c];
#pragma unroll
        for (int s = 0; s < 7; ++s) {
            const float* rp = base + (s + 2) * 30;
            float2 cL = *(const float2*)&rp[0];
            float2 cH = *(const float2*)&rp[2];
            float o0 = w0 * a0 + w1 * a1 + w2 * a2
                     + w3 * b0 + w4 * b1 + w5 * b2
                     + w6 * cL.x + w7 * cL.y + w8 * cH.x;
            float o1 = w0 * a1 + w1 * a2 + w2 * a3
                     + w3 * b1 + w4 * b2 + w5 * b3
                     + w6 * cL.y + w7 * cH.x + w8 * cH.y;
            *(float2*)&op[s * 28] = make_float2(o0, o1);
            a0 = b0; a1 = b1; a2 = b2; a3 = b3;
            b0 = cL.x; b1 = cL.y; b2 = cH.x; b3 = cH.y;
        }
    }
    __syncthreads();

    // ---- stage 5: partial logits; Wc2Q linear in t2's LDS order ----
    float acc[10];
#pragma unroll
    for (int n = 0; n < 10; ++n) acc[n] = 0.f;
    const float* wbase = &Wc2Q[q * 3136];
    for (int k = tid; k < 784; k += NT) {         // 784 float4 chunks
        float4 tv = *(const float4*)&sB[k * 4];
#pragma unroll
        for (int n = 0; n < 10; ++n) {
            float4 wv = *(const float4*)&wbase[n * 12544 + k * 4];
            acc[n] += tv.x * wv.x + tv.y * wv.y + tv.z * wv.z + tv.w * wv.w;
        }
    }
#pragma unroll
    for (int n = 0; n < 10; ++n) {
        float v = acc[n];
#pragma unroll
        for (int off = 32; off > 0; off >>= 1)
            v += __shfl_down(v, off, 64);
        if ((tid & 63) == 0) sred[(tid >> 6) * 10 + n] = v;
    }
    __syncthreads();
    if (tid < 10) {
        float lg = sred[tid] + sred[10 + tid] + sred[20 + tid] + sred[30 + tid];
        atomicAdd(&Lg[b * 10 + tid], lg);
    }
    // ---- last-arriving quarter computes bias + log_softmax ----
    if (tid == 0) {
        __threadfence();
        unsigned int old = atomicAdd(&Cnt[b], 1u);
        sflag = (old == 3u) ? 1 : 0;
    }
    __syncthreads();
    if (sflag) {
        if (tid < 10) {
            float v = atomicAdd(&Lg[b * 10 + tid], 0.0f) + b_cls[tid];
            slog[tid] = v;
        }
        __syncthreads();
        if (tid < 10) {
            float m = -1e30f;
#pragma unroll
            for (int n = 0; n < 10; ++n) m = fmaxf(m, slog[n]);
            float s = 0.f;
#pragma unroll
            for (int n = 0; n < 10; ++n) s += expf(slog[n] - m);
            out[b * 10 + tid] = slog[tid] - m - logf(s);
        }
    }
}

extern "C" void kernel_launch(void* const* d_in, const int* in_sizes, int n_in,
                              void* d_out, int out_size, void* d_ws, size_t ws_size,
                              hipStream_t stream) {
    const float* x     = (const float*)d_in[0];
    const float* l1_f0 = (const float*)d_in[1];
    const float* l1_f1 = (const float*)d_in[2];
    const float* l1_f2 = (const float*)d_in[3];
    const float* l1_f3 = (const float*)d_in[4];
    const float* l2_f0 = (const float*)d_in[5];
    const float* l2_f1 = (const float*)d_in[6];
    const float* l2_f2 = (const float*)d_in[7];
    const float* l2_f3 = (const float*)d_in[8];
    const float* Wcls  = (const float*)d_in[9];
    const float* bcls  = (const float*)d_in[10];
    float* out = (float*)d_out;

    float* Wc2Q = (float*)d_ws;                    // 10*12544 floats
    float* Mm   = Wc2Q + 10 * 12544;               // 256 floats
    float* Lg   = Mm + 256;                        // 5120 floats
    unsigned int* Cnt = (unsigned int*)(Lg + 5120);// 512 uints

    precomp_kernel<<<dim3(31), dim3(256), 0, stream>>>(
        l1_f0, l2_f0, l2_f3, Wcls, Wc2Q, Mm, Lg, Cnt);
    fused_quarter_kernel<<<dim3(2048), dim3(NT), 0, stream>>>(
        x, l1_f1, l1_f2, l1_f3, l2_f1, l2_f2, Wc2Q, Mm, bcls, Lg, Cnt, out);
}